// Round 4
// baseline (536.234 us; speedup 1.0000x reference)
//
#include <hip/hip_runtime.h>
#include <hip/hip_bf16.h>

#define EPS 1e-5f

typedef __hip_bfloat16 bf16;
typedef __attribute__((ext_vector_type(8))) short short8v;   // 8 bf16 = 4 VGPRs
typedef __attribute__((ext_vector_type(4))) float f32x4;

// ---------------------------------------------------------------------------
// global -> LDS direct copy, 16B per lane
// ---------------------------------------------------------------------------
__device__ inline void load_lds16(const void* g, void* l) {
  __builtin_amdgcn_global_load_lds(
      (const __attribute__((address_space(1))) void*)g,
      (__attribute__((address_space(3))) void*)l, 16, 0, 0);
}

// ---------------------------------------------------------------------------
// f32 -> bf16 elementwise (weights), 4 elems/thread
// ---------------------------------------------------------------------------
__global__ __launch_bounds__(256) void cvt_bf16_kernel(
    const float* __restrict__ in, bf16* __restrict__ out, int n4) {
  int i = blockIdx.x * 256 + threadIdx.x;
  if (i >= n4) return;
  float4 v = reinterpret_cast<const float4*>(in)[i];
  union { ushort4 u; bf16 h[4]; } cv;
  cv.h[0] = __float2bfloat16(v.x);
  cv.h[1] = __float2bfloat16(v.y);
  cv.h[2] = __float2bfloat16(v.z);
  cv.h[3] = __float2bfloat16(v.w);
  reinterpret_cast<ushort4*>(out)[i] = cv.u;
}

// ---------------------------------------------------------------------------
// LayerNorm over last dim = 256 -> bf16 output. One wave per row.
// ---------------------------------------------------------------------------
__global__ __launch_bounds__(64) void ln256_bf_kernel(
    const float* __restrict__ in, bf16* __restrict__ out,
    const float* __restrict__ g, const float* __restrict__ b) {
  int row = blockIdx.x;
  int lane = threadIdx.x;
  float4 x = reinterpret_cast<const float4*>(in + (size_t)row * 256)[lane];
  float s = x.x + x.y + x.z + x.w;
  float sq = x.x * x.x + x.y * x.y + x.z * x.z + x.w * x.w;
#pragma unroll
  for (int off = 32; off >= 1; off >>= 1) {
    s += __shfl_xor(s, off);
    sq += __shfl_xor(sq, off);
  }
  float mean = s * (1.0f / 256.0f);
  float inv = rsqrtf(sq * (1.0f / 256.0f) - mean * mean + EPS);
  float4 gv = reinterpret_cast<const float4*>(g)[lane];
  float4 bv = reinterpret_cast<const float4*>(b)[lane];
  union { ushort4 u; bf16 h[4]; } cv;
  cv.h[0] = __float2bfloat16((x.x - mean) * inv * gv.x + bv.x);
  cv.h[1] = __float2bfloat16((x.y - mean) * inv * gv.y + bv.y);
  cv.h[2] = __float2bfloat16((x.z - mean) * inv * gv.z + bv.z);
  cv.h[3] = __float2bfloat16((x.w - mean) * inv * gv.w + bv.w);
  reinterpret_cast<ushort4*>(out + (size_t)row * 256)[lane] = cv.u;
}

// ---------------------------------------------------------------------------
// Fused pair LayerNorm + bias einsum: bT[h][k][q] (fp32)
// ---------------------------------------------------------------------------
__global__ __launch_bounds__(64) void pair_bias_kernel(
    const float* __restrict__ pair, const float* __restrict__ g,
    const float* __restrict__ b, const float* __restrict__ bw,
    float* __restrict__ bT) {
  int idx = blockIdx.x;  // q*256 + k
  int q = idx >> 8;
  int k = idx & 255;
  int lane = threadIdx.x;
  float2 z = reinterpret_cast<const float2*>(pair + (size_t)idx * 128)[lane];
  float s = z.x + z.y;
  float sq = z.x * z.x + z.y * z.y;
#pragma unroll
  for (int off = 32; off >= 1; off >>= 1) {
    s += __shfl_xor(s, off);
    sq += __shfl_xor(sq, off);
  }
  float mean = s * (1.0f / 128.0f);
  float inv = rsqrtf(sq * (1.0f / 128.0f) - mean * mean + EPS);
  float2 gv = reinterpret_cast<const float2*>(g)[lane];
  float2 bv = reinterpret_cast<const float2*>(b)[lane];
  float z0 = (z.x - mean) * inv * gv.x + bv.x;
  float z1 = (z.y - mean) * inv * gv.y + bv.y;
#pragma unroll
  for (int h = 0; h < 8; ++h) {
    float2 w = reinterpret_cast<const float2*>(bw + h * 128)[lane];
    float p = z0 * w.x + z1 * w.y;
#pragma unroll
    for (int off = 32; off >= 1; off >>= 1) p += __shfl_xor(p, off);
    if (lane == 0) bT[((size_t)h * 256 + k) * 256 + q] = p;
  }
}

// ---------------------------------------------------------------------------
// MFMA GEMM: out[M,N] = A[M,K] @ W[N,K]^T (+bias +epilogue), bf16 in, fp32 acc
// EPI 0: bf16 out = acc + bias                     (qkv+gate)
// EPI 2: fp32 out = aux + acc + bias               (residual)
// EPI 3: bf16 out = relu(acc + bias)               (transition hidden)
// ---------------------------------------------------------------------------
template <int EPI>
__global__ __launch_bounds__(256) void gemm_mfma_kernel(
    const bf16* __restrict__ A, const bf16* __restrict__ W,
    const float* __restrict__ bias, const float* __restrict__ aux, void* out,
    int N, int K) {
  __shared__ __align__(16) short As[128 * 32];
  __shared__ __align__(16) short Bs[128 * 32];
  int bm = blockIdx.x, bn = blockIdx.y;
  int tid = threadIdx.x;
  int w = tid >> 6, lane = tid & 63;
  int wr = w >> 1, wc = w & 1;
  int c0 = w * 64 + lane;
  int srow = c0 >> 2, skq = c0 & 3;
  const short* Abase = (const short*)(A + (size_t)(bm * 128) * K);
  const short* Wbase = (const short*)(W + (size_t)(bn * 128) * K);
  f32x4 acc[4][4] = {};
  int lrow = lane & 15, kq = lane >> 4;

  for (int k0 = 0; k0 < K; k0 += 32) {
    __syncthreads();
    load_lds16(Abase + (size_t)srow * K + k0 + skq * 8, &As[c0 * 8]);
    load_lds16(Abase + (size_t)(srow + 64) * K + k0 + skq * 8,
               &As[(256 + c0) * 8]);
    load_lds16(Wbase + (size_t)srow * K + k0 + skq * 8, &Bs[c0 * 8]);
    load_lds16(Wbase + (size_t)(srow + 64) * K + k0 + skq * 8,
               &Bs[(256 + c0) * 8]);
    __syncthreads();
    short8v af[4], bfv[4];
#pragma unroll
    for (int i = 0; i < 4; ++i)
      af[i] = *reinterpret_cast<const short8v*>(
          &As[(wr * 64 + i * 16 + lrow) * 32 + kq * 8]);
#pragma unroll
    for (int j = 0; j < 4; ++j)
      bfv[j] = *reinterpret_cast<const short8v*>(
          &Bs[(wc * 64 + j * 16 + lrow) * 32 + kq * 8]);
#pragma unroll
    for (int i = 0; i < 4; ++i)
#pragma unroll
      for (int j = 0; j < 4; ++j)
        acc[i][j] = __builtin_amdgcn_mfma_f32_16x16x32_bf16(af[i], bfv[j],
                                                            acc[i][j], 0, 0, 0);
  }

  float* outF = (float*)out;
  bf16* outB = (bf16*)out;
  int r4 = (lane >> 4) * 4;
#pragma unroll
  for (int j = 0; j < 4; ++j) {
    int c = bn * 128 + wc * 64 + j * 16 + lrow;
    float bv = bias ? bias[c] : 0.0f;
#pragma unroll
    for (int i = 0; i < 4; ++i) {
      int r0 = bm * 128 + wr * 64 + i * 16 + r4;
#pragma unroll
      for (int reg = 0; reg < 4; ++reg) {
        size_t off = (size_t)(r0 + reg) * N + c;
        float v = acc[i][j][reg] + bv;
        if (EPI == 0) {
          outB[off] = __float2bfloat16(v);
        } else if (EPI == 2) {
          outF[off] = v + aux[off];
        } else {
          outB[off] = __float2bfloat16(fmaxf(v, 0.0f));
        }
      }
    }
  }
}

// ---------------------------------------------------------------------------
// MFMA flash attention + fused gating.
// qkvg rows of 1024: [q(256)|k(256)|v(256)|gate(256)], head h at h*32.
// ROWMODE: block=(s,h), 256 q, 256 kv, pair bias.  !ROWMODE: block=(r,h),
// 128 q (s-dim), 128 kv, no bias. 4 waves, wave owns QT*16 q-rows.
// Swapped QK^T -> S^T frags; per-q-tile P round-trip through 2KB/wave LDS;
// epilogue: out = O * sigmoid(gate), bf16.
// ---------------------------------------------------------------------------
template <bool ROWMODE>
__global__ __launch_bounds__(256, 4) void attn_mfma_kernel(
    const bf16* __restrict__ qkv, const float* __restrict__ bT,
    bf16* __restrict__ o) {
  constexpr int KVLEN = ROWMODE ? 256 : 128;
  constexpr int QT = ROWMODE ? 4 : 2;          // q-tiles (16 rows) per wave
  constexpr int KOUT = KVLEN / 64;             // k-chunks of 64
  constexpr int STRIDE = ROWMODE ? 1024 : 1024 * 256;  // elems between rows
  constexpr int OSTRIDE = ROWMODE ? 256 : 256 * 256;
  __shared__ __align__(16) short K_lds[KVLEN * 32];    // [k][c] swizzled
  __shared__ __align__(16) short Vt_lds[32 * KVLEN];   // [c][k] swizzled
  __shared__ __align__(16) short P_lds[4][16 * 64];    // per-wave, one q-tile

  int b = blockIdx.x;
  int idx = b >> 3, h = b & 7;
  const short* qb =
      (const short*)qkv + (size_t)idx * (ROWMODE ? 262144 : 1024);
  const bf16* qbh = (const bf16*)qb;
  bf16* ob = o + (size_t)idx * (ROWMODE ? 65536 : 256);
  int tid = threadIdx.x;
  int w = tid >> 6, lane = tid & 63;
  int l15 = lane & 15, l4 = lane >> 4;

  // ---- stage K via global_load_lds, source pre-swizzled (m173) ----
#pragma unroll
  for (int rnd = 0; rnd < KVLEN / 64; ++rnd) {
    int c = rnd * 256 + tid;
    int row = c >> 2;
    int kq = (c & 3) ^ ((row >> 1) & 3);
    load_lds16(qb + (size_t)row * STRIDE + 256 + h * 32 + kq * 8,
               &K_lds[c * 8]);
  }
  // ---- stage V transposed + swizzled (reg-staged, pack k-pairs) ----
#pragma unroll
  for (int it = 0; it < KVLEN / 128; ++it) {
    int tt = it * 256 + tid;
    int kp = tt >> 2;
    int cc = (tt & 3) * 8;
    short8v va = *reinterpret_cast<const short8v*>(
        qb + (size_t)(2 * kp) * STRIDE + 512 + h * 32 + cc);
    short8v vb = *reinterpret_cast<const short8v*>(
        qb + (size_t)(2 * kp + 1) * STRIDE + 512 + h * 32 + cc);
    int k = 2 * kp;
    int u = k >> 3;
    int klo = k & 7;
#pragma unroll
    for (int e = 0; e < 8; ++e) {
      int cI = cc + e;
      int up = u ^ (cI & 7);
      unsigned pk =
          (unsigned)(unsigned short)va[e] | ((unsigned)(unsigned short)vb[e] << 16);
      *reinterpret_cast<unsigned*>(&Vt_lds[cI * KVLEN + up * 8 + klo]) = pk;
    }
  }
  __syncthreads();

  // ---- Q fragments (B-operand): lane = q row l15, c-chunk l4*8 ----
  int q0 = w * QT * 16;
  short8v qf[QT];
#pragma unroll
  for (int j = 0; j < QT; ++j)
    qf[j] = *reinterpret_cast<const short8v*>(
        qb + (size_t)(q0 + j * 16 + l15) * STRIDE + h * 32 + l4 * 8);

  float mrun[QT], lrun[QT];
#pragma unroll
  for (int j = 0; j < QT; ++j) { mrun[j] = -3.0e38f; lrun[j] = 0.0f; }
  f32x4 acc_o[QT][2] = {};

  const float SC = 0.17677669529663687f;  // 32^-0.5
  const float L2E = 1.4426950408889634f;
  const f32x4 zf = {0.f, 0.f, 0.f, 0.f};
  int qs = l15 & 7;

#pragma unroll 1
  for (int kt = 0; kt < KOUT; ++kt) {
    // hoist K and V fragments for this 64-k chunk
    short8v kf[4];
#pragma unroll
    for (int i = 0; i < 4; ++i) {
      int krow = kt * 64 + i * 16 + l15;
      kf[i] = *reinterpret_cast<const short8v*>(
          &K_lds[krow * 32 + ((l4 ^ ((krow >> 1) & 3)) * 8)]);
    }
    short8v vf[2][2];
#pragma unroll
    for (int ks = 0; ks < 2; ++ks)
#pragma unroll
      for (int ct = 0; ct < 2; ++ct) {
        int c = ct * 16 + l15;
        int u = kt * 8 + ks * 4 + l4;
        vf[ks][ct] = *reinterpret_cast<const short8v*>(
            &Vt_lds[c * KVLEN + (u ^ (c & 7)) * 8]);
      }

#pragma unroll
    for (int j = 0; j < QT; ++j) {
      // ---- QK^T: S^T [64k][16q] ----
      f32x4 accs[4];
#pragma unroll
      for (int i = 0; i < 4; ++i)
        accs[i] = __builtin_amdgcn_mfma_f32_16x16x32_bf16(kf[i], qf[j], zf,
                                                          0, 0, 0);
      // ---- logits = S*scale (+bias) ----
#pragma unroll
      for (int i = 0; i < 4; ++i)
#pragma unroll
        for (int r = 0; r < 4; ++r) {
          float v = accs[i][r] * SC;
          if (ROWMODE) {
            int kg = kt * 64 + i * 16 + l4 * 4 + r;
            int qg = q0 + j * 16 + l15;
            v += bT[(size_t)h * 65536 + (size_t)kg * 256 + qg];
          }
          accs[i][r] = v;
        }
      // ---- online softmax (per q = l15) ----
      float mx = -3.0e38f;
#pragma unroll
      for (int i = 0; i < 4; ++i)
#pragma unroll
        for (int r = 0; r < 4; ++r) mx = fmaxf(mx, accs[i][r]);
      mx = fmaxf(mx, __shfl_xor(mx, 16));
      mx = fmaxf(mx, __shfl_xor(mx, 32));
      float mnew = fmaxf(mrun[j], mx);
      float corr = exp2f((mrun[j] - mnew) * L2E);
      mrun[j] = mnew;
      float sum = 0.0f;
#pragma unroll
      for (int i = 0; i < 4; ++i)
#pragma unroll
        for (int r = 0; r < 4; ++r) {
          float p = exp2f((accs[i][r] - mnew) * L2E);
          accs[i][r] = p;
          sum += p;
        }
      sum += __shfl_xor(sum, 16);
      sum += __shfl_xor(sum, 32);
      lrun[j] = lrun[j] * corr + sum;
      // rescale O accumulator (corr broadcast to D-layout rows)
#pragma unroll
      for (int r = 0; r < 4; ++r) {
        float cr = __shfl(corr, l4 * 4 + r);
        acc_o[j][0][r] *= cr;
        acc_o[j][1][r] *= cr;
      }
      // ---- pack P -> per-wave LDS [q=16][k=64], swizzled ----
#pragma unroll
      for (int i = 0; i < 4; ++i) {
        union { short4 s4; bf16 h4[4]; } pk;
#pragma unroll
        for (int r = 0; r < 4; ++r) pk.h4[r] = __float2bfloat16(accs[i][r]);
        int unit = i * 2 + (l4 >> 1);
        int off = (l4 & 1) * 4;
        *reinterpret_cast<short4*>(
            &P_lds[w][l15 * 64 + (unit ^ qs) * 8 + off]) = pk.s4;
      }
      // ---- PV: acc_o += P @ V (same wave; compiler inserts lgkmcnt) ----
#pragma unroll
      for (int ks = 0; ks < 2; ++ks) {
        short8v pf = *reinterpret_cast<const short8v*>(
            &P_lds[w][l15 * 64 + ((ks * 4 + l4) ^ qs) * 8]);
#pragma unroll
        for (int ct = 0; ct < 2; ++ct)
          acc_o[j][ct] = __builtin_amdgcn_mfma_f32_16x16x32_bf16(
              pf, vf[ks][ct], acc_o[j][ct], 0, 0, 0);
      }
    }
  }

  // ---- epilogue: out = (O/l) * sigmoid(gate), bf16 ----
#pragma unroll
  for (int j = 0; j < QT; ++j) {
    float inv = 1.0f / lrun[j];
#pragma unroll
    for (int r = 0; r < 4; ++r) {
      float rv = __shfl(inv, l4 * 4 + r);
      int row = q0 + j * 16 + l4 * 4 + r;
      const bf16* grow = qbh + (size_t)row * STRIDE + 768 + h * 32;
      bf16* orow = ob + (size_t)row * OSTRIDE + h * 32;
#pragma unroll
      for (int ct = 0; ct < 2; ++ct) {
        int c = ct * 16 + l15;
        float gt = __bfloat162float(grow[c]);
        float sg = 1.0f / (1.0f + __expf(-gt));
        orow[c] = __float2bfloat16(acc_o[j][ct][r] * rv * sg);
      }
    }
  }
}

// ---------------------------------------------------------------------------
extern "C" void kernel_launch(void* const* d_in, const int* in_sizes, int n_in,
                              void* d_out, int out_size, void* d_ws,
                              size_t ws_size, hipStream_t stream) {
  (void)in_sizes; (void)n_in; (void)out_size; (void)ws_size;
  const float* node      = (const float*)d_in[0];
  const float* pair      = (const float*)d_in[1];
  const float* ln_mr_g   = (const float*)d_in[2];
  const float* ln_mr_b   = (const float*)d_in[3];
  const float* ln_z_g    = (const float*)d_in[4];
  const float* ln_z_b    = (const float*)d_in[5];
  const float* b_weights = (const float*)d_in[6];
  const float* row_qkv_w = (const float*)d_in[7];
  const float* row_qkv_b = (const float*)d_in[8];
  const float* row_gate_w= (const float*)d_in[9];
  const float* row_gate_b= (const float*)d_in[10];
  const float* row_o_w   = (const float*)d_in[11];
  const float* out_bias  = (const float*)d_in[12];
  const float* ln_mc_g   = (const float*)d_in[13];
  const float* ln_mc_b   = (const float*)d_in[14];
  const float* col_qkv_w = (const float*)d_in[15];
  const float* col_qkv_b = (const float*)d_in[16];
  const float* col_gate_w= (const float*)d_in[17];
  const float* col_gate_b= (const float*)d_in[18];
  const float* col_o_w   = (const float*)d_in[19];
  const float* col_o_b   = (const float*)d_in[20];
  const float* ln_t_g    = (const float*)d_in[21];
  const float* ln_t_b    = (const float*)d_in[22];
  const float* t_w1      = (const float*)d_in[23];
  const float* t_b1      = (const float*)d_in[24];
  const float* t_w2      = (const float*)d_in[25];
  const float* t_b2      = (const float*)d_in[26];
  float* out = (float*)d_out;

  const size_t NR = 32768;
  char* p = (char*)d_ws;
  float* buf_node = (float*)p; p += NR * 256 * 4;
  char*  qkv_region = p;       p += NR * 1024 * 2;   // qkvg bf16 / h_bf
  float* buf_bias = (float*)p; p += 8 * 256 * 256 * 4;
  bf16* ln_bf     = (bf16*)p;  p += NR * 256 * 2;
  bf16* g_bf      = (bf16*)p;  p += NR * 256 * 2;    // gated attn out (bf16)
  bf16* qkv_bf = (bf16*)qkv_region;   // [32768][1024]: q|k|v|gate
  bf16* h_bf   = (bf16*)qkv_region;   // phase C: [32768][1024]
  bf16* w_rqkvg = (bf16*)p; p += 1024 * 256 * 2;
  bf16* w_ro    = (bf16*)p; p += 256 * 256 * 2;
  bf16* w_cqkvg = (bf16*)p; p += 1024 * 256 * 2;
  bf16* w_co    = (bf16*)p; p += 256 * 256 * 2;
  bf16* w_t1    = (bf16*)p; p += 1024 * 256 * 2;
  bf16* w_t2    = (bf16*)p; p += 256 * 1024 * 2;
  float* b_rqkvg = (float*)p; p += 1024 * 4;
  float* b_cqkvg = (float*)p; p += 1024 * 4;

  // ---- weight conversions / concatenation (fp32 -> bf16) ----
  cvt_bf16_kernel<<<192, 256, 0, stream>>>(row_qkv_w, w_rqkvg, 49152);
  cvt_bf16_kernel<<<64, 256, 0, stream>>>(row_gate_w, w_rqkvg + 768 * 256,
                                          16384);
  cvt_bf16_kernel<<<64, 256, 0, stream>>>(row_o_w, w_ro, 16384);
  cvt_bf16_kernel<<<192, 256, 0, stream>>>(col_qkv_w, w_cqkvg, 49152);
  cvt_bf16_kernel<<<64, 256, 0, stream>>>(col_gate_w, w_cqkvg + 768 * 256,
                                          16384);
  cvt_bf16_kernel<<<64, 256, 0, stream>>>(col_o_w, w_co, 16384);
  cvt_bf16_kernel<<<256, 256, 0, stream>>>(t_w1, w_t1, 65536);
  cvt_bf16_kernel<<<256, 256, 0, stream>>>(t_w2, w_t2, 65536);
  hipMemcpyAsync(b_rqkvg, row_qkv_b, 768 * 4, hipMemcpyDeviceToDevice, stream);
  hipMemcpyAsync(b_rqkvg + 768, row_gate_b, 256 * 4, hipMemcpyDeviceToDevice,
                 stream);
  hipMemcpyAsync(b_cqkvg, col_qkv_b, 768 * 4, hipMemcpyDeviceToDevice, stream);
  hipMemcpyAsync(b_cqkvg + 768, col_gate_b, 256 * 4, hipMemcpyDeviceToDevice,
                 stream);

  // ---- Phase A: MSARowAttentionWithPairBias ----
  ln256_bf_kernel<<<32768, 64, 0, stream>>>(node, ln_bf, ln_mr_g, ln_mr_b);
  pair_bias_kernel<<<65536, 64, 0, stream>>>(pair, ln_z_g, ln_z_b, b_weights,
                                             buf_bias);
  gemm_mfma_kernel<0><<<dim3(256, 8), 256, 0, stream>>>(
      ln_bf, w_rqkvg, b_rqkvg, nullptr, qkv_bf, 1024, 256);
  attn_mfma_kernel<true><<<1024, 256, 0, stream>>>(qkv_bf, buf_bias, g_bf);
  gemm_mfma_kernel<2><<<dim3(256, 2), 256, 0, stream>>>(
      g_bf, w_ro, out_bias, node, buf_node, 256, 256);

  // ---- Phase B: MSAColumnAttention ----
  ln256_bf_kernel<<<32768, 64, 0, stream>>>(buf_node, ln_bf, ln_mc_g, ln_mc_b);
  gemm_mfma_kernel<0><<<dim3(256, 8), 256, 0, stream>>>(
      ln_bf, w_cqkvg, b_cqkvg, nullptr, qkv_bf, 1024, 256);
  attn_mfma_kernel<false><<<2048, 256, 0, stream>>>(qkv_bf, nullptr, g_bf);
  gemm_mfma_kernel<2><<<dim3(256, 2), 256, 0, stream>>>(
      g_bf, w_co, col_o_b, buf_node, buf_node, 256, 256);

  // ---- Phase C: MSATransition ----
  ln256_bf_kernel<<<32768, 64, 0, stream>>>(buf_node, ln_bf, ln_t_g, ln_t_b);
  gemm_mfma_kernel<3><<<dim3(256, 8), 256, 0, stream>>>(
      ln_bf, w_t1, t_b1, nullptr, h_bf, 1024, 256);
  gemm_mfma_kernel<2><<<dim3(256, 2), 256, 0, stream>>>(
      h_bf, w_t2, t_b2, buf_node, out, 256, 1024);
}

// Round 5
// 398.552 us; speedup vs baseline: 1.3455x; 1.3455x over previous
//
#include <hip/hip_runtime.h>
#include <hip/hip_bf16.h>

#define EPS 1e-5f

typedef __hip_bfloat16 bf16;
typedef __attribute__((ext_vector_type(8))) short short8v;   // 8 bf16 = 4 VGPRs
typedef __attribute__((ext_vector_type(4))) float f32x4;

// ---------------------------------------------------------------------------
// global -> LDS direct copy, 16B per lane
// ---------------------------------------------------------------------------
__device__ inline void load_lds16(const void* g, void* l) {
  __builtin_amdgcn_global_load_lds(
      (const __attribute__((address_space(1))) void*)g,
      (__attribute__((address_space(3))) void*)l, 16, 0, 0);
}

// ---------------------------------------------------------------------------
// f32 -> bf16 elementwise (weights), 4 elems/thread
// ---------------------------------------------------------------------------
__global__ __launch_bounds__(256) void cvt_bf16_kernel(
    const float* __restrict__ in, bf16* __restrict__ out, int n4) {
  int i = blockIdx.x * 256 + threadIdx.x;
  if (i >= n4) return;
  float4 v = reinterpret_cast<const float4*>(in)[i];
  union { ushort4 u; bf16 h[4]; } cv;
  cv.h[0] = __float2bfloat16(v.x);
  cv.h[1] = __float2bfloat16(v.y);
  cv.h[2] = __float2bfloat16(v.z);
  cv.h[3] = __float2bfloat16(v.w);
  reinterpret_cast<ushort4*>(out)[i] = cv.u;
}

// ---------------------------------------------------------------------------
// LayerNorm over last dim = 256 -> bf16 output. One wave per row.
// ---------------------------------------------------------------------------
__global__ __launch_bounds__(64) void ln256_bf_kernel(
    const float* __restrict__ in, bf16* __restrict__ out,
    const float* __restrict__ g, const float* __restrict__ b) {
  int row = blockIdx.x;
  int lane = threadIdx.x;
  float4 x = reinterpret_cast<const float4*>(in + (size_t)row * 256)[lane];
  float s = x.x + x.y + x.z + x.w;
  float sq = x.x * x.x + x.y * x.y + x.z * x.z + x.w * x.w;
#pragma unroll
  for (int off = 32; off >= 1; off >>= 1) {
    s += __shfl_xor(s, off);
    sq += __shfl_xor(sq, off);
  }
  float mean = s * (1.0f / 256.0f);
  float inv = rsqrtf(sq * (1.0f / 256.0f) - mean * mean + EPS);
  float4 gv = reinterpret_cast<const float4*>(g)[lane];
  float4 bv = reinterpret_cast<const float4*>(b)[lane];
  union { ushort4 u; bf16 h[4]; } cv;
  cv.h[0] = __float2bfloat16((x.x - mean) * inv * gv.x + bv.x);
  cv.h[1] = __float2bfloat16((x.y - mean) * inv * gv.y + bv.y);
  cv.h[2] = __float2bfloat16((x.z - mean) * inv * gv.z + bv.z);
  cv.h[3] = __float2bfloat16((x.w - mean) * inv * gv.w + bv.w);
  reinterpret_cast<ushort4*>(out + (size_t)row * 256)[lane] = cv.u;
}

// ---------------------------------------------------------------------------
// Fused pair LayerNorm + bias einsum: bT[h][k][q] (fp32)
// ---------------------------------------------------------------------------
__global__ __launch_bounds__(64) void pair_bias_kernel(
    const float* __restrict__ pair, const float* __restrict__ g,
    const float* __restrict__ b, const float* __restrict__ bw,
    float* __restrict__ bT) {
  int idx = blockIdx.x;  // q*256 + k
  int q = idx >> 8;
  int k = idx & 255;
  int lane = threadIdx.x;
  float2 z = reinterpret_cast<const float2*>(pair + (size_t)idx * 128)[lane];
  float s = z.x + z.y;
  float sq = z.x * z.x + z.y * z.y;
#pragma unroll
  for (int off = 32; off >= 1; off >>= 1) {
    s += __shfl_xor(s, off);
    sq += __shfl_xor(sq, off);
  }
  float mean = s * (1.0f / 128.0f);
  float inv = rsqrtf(sq * (1.0f / 128.0f) - mean * mean + EPS);
  float2 gv = reinterpret_cast<const float2*>(g)[lane];
  float2 bv = reinterpret_cast<const float2*>(b)[lane];
  float z0 = (z.x - mean) * inv * gv.x + bv.x;
  float z1 = (z.y - mean) * inv * gv.y + bv.y;
#pragma unroll
  for (int h = 0; h < 8; ++h) {
    float2 w = reinterpret_cast<const float2*>(bw + h * 128)[lane];
    float p = z0 * w.x + z1 * w.y;
#pragma unroll
    for (int off = 32; off >= 1; off >>= 1) p += __shfl_xor(p, off);
    if (lane == 0) bT[((size_t)h * 256 + k) * 256 + q] = p;
  }
}

// ---------------------------------------------------------------------------
// MFMA GEMM: out[M,N] = A[M,K] @ W[N,K]^T (+bias +epilogue), bf16 in, fp32 acc
// EPI 0: bf16 out = acc + bias                     (qkv+gate)
// EPI 2: fp32 out = aux + acc + bias               (residual)
// EPI 3: bf16 out = relu(acc + bias)               (transition hidden)
// ---------------------------------------------------------------------------
template <int EPI>
__global__ __launch_bounds__(256) void gemm_mfma_kernel(
    const bf16* __restrict__ A, const bf16* __restrict__ W,
    const float* __restrict__ bias, const float* __restrict__ aux, void* out,
    int N, int K) {
  __shared__ __align__(16) short As[128 * 32];
  __shared__ __align__(16) short Bs[128 * 32];
  int bm = blockIdx.x, bn = blockIdx.y;
  int tid = threadIdx.x;
  int w = tid >> 6, lane = tid & 63;
  int wr = w >> 1, wc = w & 1;
  int c0 = w * 64 + lane;
  int srow = c0 >> 2, skq = c0 & 3;
  const short* Abase = (const short*)(A + (size_t)(bm * 128) * K);
  const short* Wbase = (const short*)(W + (size_t)(bn * 128) * K);
  f32x4 acc[4][4] = {};
  int lrow = lane & 15, kq = lane >> 4;

  for (int k0 = 0; k0 < K; k0 += 32) {
    __syncthreads();
    load_lds16(Abase + (size_t)srow * K + k0 + skq * 8, &As[c0 * 8]);
    load_lds16(Abase + (size_t)(srow + 64) * K + k0 + skq * 8,
               &As[(256 + c0) * 8]);
    load_lds16(Wbase + (size_t)srow * K + k0 + skq * 8, &Bs[c0 * 8]);
    load_lds16(Wbase + (size_t)(srow + 64) * K + k0 + skq * 8,
               &Bs[(256 + c0) * 8]);
    __syncthreads();
    short8v af[4], bfv[4];
#pragma unroll
    for (int i = 0; i < 4; ++i)
      af[i] = *reinterpret_cast<const short8v*>(
          &As[(wr * 64 + i * 16 + lrow) * 32 + kq * 8]);
#pragma unroll
    for (int j = 0; j < 4; ++j)
      bfv[j] = *reinterpret_cast<const short8v*>(
          &Bs[(wc * 64 + j * 16 + lrow) * 32 + kq * 8]);
#pragma unroll
    for (int i = 0; i < 4; ++i)
#pragma unroll
      for (int j = 0; j < 4; ++j)
        acc[i][j] = __builtin_amdgcn_mfma_f32_16x16x32_bf16(af[i], bfv[j],
                                                            acc[i][j], 0, 0, 0);
  }

  float* outF = (float*)out;
  bf16* outB = (bf16*)out;
  int r4 = (lane >> 4) * 4;
#pragma unroll
  for (int j = 0; j < 4; ++j) {
    int c = bn * 128 + wc * 64 + j * 16 + lrow;
    float bv = bias ? bias[c] : 0.0f;
#pragma unroll
    for (int i = 0; i < 4; ++i) {
      int r0 = bm * 128 + wr * 64 + i * 16 + r4;
#pragma unroll
      for (int reg = 0; reg < 4; ++reg) {
        size_t off = (size_t)(r0 + reg) * N + c;
        float v = acc[i][j][reg] + bv;
        if (EPI == 0) {
          outB[off] = __float2bfloat16(v);
        } else if (EPI == 2) {
          outF[off] = v + aux[off];
        } else {
          outB[off] = __float2bfloat16(fmaxf(v, 0.0f));
        }
      }
    }
  }
}

// ---------------------------------------------------------------------------
// MFMA flash attention + fused gating.
// qkvg rows of 1024: [q(256)|k(256)|v(256)|gate(256)], head h at h*32.
// ROWMODE: block=(s,h), 256 q, 256 kv, pair bias.  !ROWMODE: block=(r,h),
// 128 q (s-dim), 128 kv, no bias. 4 waves, wave owns QT*16 q-rows.
// No min-waves launch bound: round 4 showed (256,4) forces 64 VGPR + scratch
// spills (FETCH 51->225MB). Register structure trimmed to fit 128 naturally:
// kf transient in i-loop, vf[2][2] hoisted per k-chunk only.
// ---------------------------------------------------------------------------
template <bool ROWMODE>
__global__ __launch_bounds__(256) void attn_mfma_kernel(
    const bf16* __restrict__ qkv, const float* __restrict__ bT,
    bf16* __restrict__ o) {
  constexpr int KVLEN = ROWMODE ? 256 : 128;
  constexpr int QT = ROWMODE ? 4 : 2;          // q-tiles (16 rows) per wave
  constexpr int KOUT = KVLEN / 64;             // k-chunks of 64
  constexpr int STRIDE = ROWMODE ? 1024 : 1024 * 256;  // elems between rows
  constexpr int OSTRIDE = ROWMODE ? 256 : 256 * 256;
  __shared__ __align__(16) short K_lds[KVLEN * 32];    // [k][c] swizzled
  __shared__ __align__(16) short Vt_lds[32 * KVLEN];   // [c][k] swizzled
  __shared__ __align__(16) short P_lds[4][16 * 64];    // per-wave, one q-tile

  int b = blockIdx.x;
  int idx = b >> 3, h = b & 7;
  const short* qb =
      (const short*)qkv + (size_t)idx * (ROWMODE ? 262144 : 1024);
  const bf16* qbh = (const bf16*)qb;
  bf16* ob = o + (size_t)idx * (ROWMODE ? 65536 : 256);
  int tid = threadIdx.x;
  int w = tid >> 6, lane = tid & 63;
  int l15 = lane & 15, l4 = lane >> 4;

  // ---- stage K via global_load_lds, source pre-swizzled (m173) ----
#pragma unroll
  for (int rnd = 0; rnd < KVLEN / 64; ++rnd) {
    int c = rnd * 256 + tid;
    int row = c >> 2;
    int kq = (c & 3) ^ ((row >> 1) & 3);
    load_lds16(qb + (size_t)row * STRIDE + 256 + h * 32 + kq * 8,
               &K_lds[c * 8]);
  }
  // ---- stage V transposed + swizzled (reg-staged, pack k-pairs) ----
#pragma unroll
  for (int it = 0; it < KVLEN / 128; ++it) {
    int tt = it * 256 + tid;
    int kp = tt >> 2;
    int cc = (tt & 3) * 8;
    short8v va = *reinterpret_cast<const short8v*>(
        qb + (size_t)(2 * kp) * STRIDE + 512 + h * 32 + cc);
    short8v vb = *reinterpret_cast<const short8v*>(
        qb + (size_t)(2 * kp + 1) * STRIDE + 512 + h * 32 + cc);
    int k = 2 * kp;
    int u = k >> 3;
    int klo = k & 7;
#pragma unroll
    for (int e = 0; e < 8; ++e) {
      int cI = cc + e;
      int up = u ^ (cI & 7);
      unsigned pk =
          (unsigned)(unsigned short)va[e] | ((unsigned)(unsigned short)vb[e] << 16);
      *reinterpret_cast<unsigned*>(&Vt_lds[cI * KVLEN + up * 8 + klo]) = pk;
    }
  }
  __syncthreads();

  // ---- Q fragments (B-operand): lane = q row l15, c-chunk l4*8 ----
  int q0 = w * QT * 16;
  short8v qf[QT];
#pragma unroll
  for (int j = 0; j < QT; ++j)
    qf[j] = *reinterpret_cast<const short8v*>(
        qb + (size_t)(q0 + j * 16 + l15) * STRIDE + h * 32 + l4 * 8);

  float mrun[QT], lrun[QT];
#pragma unroll
  for (int j = 0; j < QT; ++j) { mrun[j] = -3.0e38f; lrun[j] = 0.0f; }
  f32x4 acc_o[QT][2] = {};

  const float SC = 0.17677669529663687f;  // 32^-0.5
  const float L2E = 1.4426950408889634f;
  const f32x4 zf = {0.f, 0.f, 0.f, 0.f};
  int qs = l15 & 7;

#pragma unroll 1
  for (int kt = 0; kt < KOUT; ++kt) {
    // hoist V fragments for this 64-k chunk (16 VGPR); K read transiently
    short8v vf[2][2];
#pragma unroll
    for (int ks = 0; ks < 2; ++ks)
#pragma unroll
      for (int ct = 0; ct < 2; ++ct) {
        int c = ct * 16 + l15;
        int u = kt * 8 + ks * 4 + l4;
        vf[ks][ct] = *reinterpret_cast<const short8v*>(
            &Vt_lds[c * KVLEN + (u ^ (c & 7)) * 8]);
      }

#pragma unroll
    for (int j = 0; j < QT; ++j) {
      // ---- QK^T: S^T [64k][16q] ----
      f32x4 accs[4];
#pragma unroll
      for (int i = 0; i < 4; ++i) {
        int krow = kt * 64 + i * 16 + l15;
        short8v kf = *reinterpret_cast<const short8v*>(
            &K_lds[krow * 32 + ((l4 ^ ((krow >> 1) & 3)) * 8)]);
        accs[i] =
            __builtin_amdgcn_mfma_f32_16x16x32_bf16(kf, qf[j], zf, 0, 0, 0);
      }
      // ---- logits = S*scale (+bias) ----
#pragma unroll
      for (int i = 0; i < 4; ++i)
#pragma unroll
        for (int r = 0; r < 4; ++r) {
          float v = accs[i][r] * SC;
          if (ROWMODE) {
            int kg = kt * 64 + i * 16 + l4 * 4 + r;
            int qg = q0 + j * 16 + l15;
            v += bT[(size_t)h * 65536 + (size_t)kg * 256 + qg];
          }
          accs[i][r] = v;
        }
      // ---- online softmax (per q = l15) ----
      float mx = -3.0e38f;
#pragma unroll
      for (int i = 0; i < 4; ++i)
#pragma unroll
        for (int r = 0; r < 4; ++r) mx = fmaxf(mx, accs[i][r]);
      mx = fmaxf(mx, __shfl_xor(mx, 16));
      mx = fmaxf(mx, __shfl_xor(mx, 32));
      float mnew = fmaxf(mrun[j], mx);
      float corr = exp2f((mrun[j] - mnew) * L2E);
      mrun[j] = mnew;
      float sum = 0.0f;
#pragma unroll
      for (int i = 0; i < 4; ++i)
#pragma unroll
        for (int r = 0; r < 4; ++r) {
          float p = exp2f((accs[i][r] - mnew) * L2E);
          accs[i][r] = p;
          sum += p;
        }
      sum += __shfl_xor(sum, 16);
      sum += __shfl_xor(sum, 32);
      lrun[j] = lrun[j] * corr + sum;
      // rescale O accumulator (corr broadcast to D-layout rows)
#pragma unroll
      for (int r = 0; r < 4; ++r) {
        float cr = __shfl(corr, l4 * 4 + r);
        acc_o[j][0][r] *= cr;
        acc_o[j][1][r] *= cr;
      }
      // ---- pack P -> per-wave LDS [q=16][k=64], swizzled ----
#pragma unroll
      for (int i = 0; i < 4; ++i) {
        union { short4 s4; bf16 h4[4]; } pk;
#pragma unroll
        for (int r = 0; r < 4; ++r) pk.h4[r] = __float2bfloat16(accs[i][r]);
        int unit = i * 2 + (l4 >> 1);
        int off = (l4 & 1) * 4;
        *reinterpret_cast<short4*>(
            &P_lds[w][l15 * 64 + (unit ^ qs) * 8 + off]) = pk.s4;
      }
      // ---- PV: acc_o += P @ V (same wave; compiler inserts lgkmcnt) ----
#pragma unroll
      for (int ks = 0; ks < 2; ++ks) {
        short8v pf = *reinterpret_cast<const short8v*>(
            &P_lds[w][l15 * 64 + ((ks * 4 + l4) ^ qs) * 8]);
#pragma unroll
        for (int ct = 0; ct < 2; ++ct)
          acc_o[j][ct] = __builtin_amdgcn_mfma_f32_16x16x32_bf16(
              pf, vf[ks][ct], acc_o[j][ct], 0, 0, 0);
      }
    }
  }

  // ---- epilogue: out = (O/l) * sigmoid(gate), bf16 ----
#pragma unroll
  for (int j = 0; j < QT; ++j) {
    float inv = 1.0f / lrun[j];
#pragma unroll
    for (int r = 0; r < 4; ++r) {
      float rv = __shfl(inv, l4 * 4 + r);
      int row = q0 + j * 16 + l4 * 4 + r;
      const bf16* grow = qbh + (size_t)row * STRIDE + 768 + h * 32;
      bf16* orow = ob + (size_t)row * OSTRIDE + h * 32;
#pragma unroll
      for (int ct = 0; ct < 2; ++ct) {
        int c = ct * 16 + l15;
        float gt = __bfloat162float(grow[c]);
        float sg = 1.0f / (1.0f + __expf(-gt));
        orow[c] = __float2bfloat16(acc_o[j][ct][r] * rv * sg);
      }
    }
  }
}

// ---------------------------------------------------------------------------
extern "C" void kernel_launch(void* const* d_in, const int* in_sizes, int n_in,
                              void* d_out, int out_size, void* d_ws,
                              size_t ws_size, hipStream_t stream) {
  (void)in_sizes; (void)n_in; (void)out_size; (void)ws_size;
  const float* node      = (const float*)d_in[0];
  const float* pair      = (const float*)d_in[1];
  const float* ln_mr_g   = (const float*)d_in[2];
  const float* ln_mr_b   = (const float*)d_in[3];
  const float* ln_z_g    = (const float*)d_in[4];
  const float* ln_z_b    = (const float*)d_in[5];
  const float* b_weights = (const float*)d_in[6];
  const float* row_qkv_w = (const float*)d_in[7];
  const float* row_qkv_b = (const float*)d_in[8];
  const float* row_gate_w= (const float*)d_in[9];
  const float* row_gate_b= (const float*)d_in[10];
  const float* row_o_w   = (const float*)d_in[11];
  const float* out_bias  = (const float*)d_in[12];
  const float* ln_mc_g   = (const float*)d_in[13];
  const float* ln_mc_b   = (const float*)d_in[14];
  const float* col_qkv_w = (const float*)d_in[15];
  const float* col_qkv_b = (const float*)d_in[16];
  const float* col_gate_w= (const float*)d_in[17];
  const float* col_gate_b= (const float*)d_in[18];
  const float* col_o_w   = (const float*)d_in[19];
  const float* col_o_b   = (const float*)d_in[20];
  const float* ln_t_g    = (const float*)d_in[21];
  const float* ln_t_b    = (const float*)d_in[22];
  const float* t_w1      = (const float*)d_in[23];
  const float* t_b1      = (const float*)d_in[24];
  const float* t_w2      = (const float*)d_in[25];
  const float* t_b2      = (const float*)d_in[26];
  float* out = (float*)d_out;

  const size_t NR = 32768;
  char* p = (char*)d_ws;
  float* buf_node = (float*)p; p += NR * 256 * 4;
  char*  qkv_region = p;       p += NR * 1024 * 2;   // qkvg bf16 / h_bf
  float* buf_bias = (float*)p; p += 8 * 256 * 256 * 4;
  bf16* ln_bf     = (bf16*)p;  p += NR * 256 * 2;
  bf16* g_bf      = (bf16*)p;  p += NR * 256 * 2;    // gated attn out (bf16)
  bf16* qkv_bf = (bf16*)qkv_region;   // [32768][1024]: q|k|v|gate
  bf16* h_bf   = (bf16*)qkv_region;   // phase C: [32768][1024]
  bf16* w_rqkvg = (bf16*)p; p += 1024 * 256 * 2;
  bf16* w_ro    = (bf16*)p; p += 256 * 256 * 2;
  bf16* w_cqkvg = (bf16*)p; p += 1024 * 256 * 2;
  bf16* w_co    = (bf16*)p; p += 256 * 256 * 2;
  bf16* w_t1    = (bf16*)p; p += 1024 * 256 * 2;
  bf16* w_t2    = (bf16*)p; p += 256 * 1024 * 2;
  float* b_rqkvg = (float*)p; p += 1024 * 4;
  float* b_cqkvg = (float*)p; p += 1024 * 4;

  // ---- weight conversions / concatenation (fp32 -> bf16) ----
  cvt_bf16_kernel<<<192, 256, 0, stream>>>(row_qkv_w, w_rqkvg, 49152);
  cvt_bf16_kernel<<<64, 256, 0, stream>>>(row_gate_w, w_rqkvg + 768 * 256,
                                          16384);
  cvt_bf16_kernel<<<64, 256, 0, stream>>>(row_o_w, w_ro, 16384);
  cvt_bf16_kernel<<<192, 256, 0, stream>>>(col_qkv_w, w_cqkvg, 49152);
  cvt_bf16_kernel<<<64, 256, 0, stream>>>(col_gate_w, w_cqkvg + 768 * 256,
                                          16384);
  cvt_bf16_kernel<<<64, 256, 0, stream>>>(col_o_w, w_co, 16384);
  cvt_bf16_kernel<<<256, 256, 0, stream>>>(t_w1, w_t1, 65536);
  cvt_bf16_kernel<<<256, 256, 0, stream>>>(t_w2, w_t2, 65536);
  hipMemcpyAsync(b_rqkvg, row_qkv_b, 768 * 4, hipMemcpyDeviceToDevice, stream);
  hipMemcpyAsync(b_rqkvg + 768, row_gate_b, 256 * 4, hipMemcpyDeviceToDevice,
                 stream);
  hipMemcpyAsync(b_cqkvg, col_qkv_b, 768 * 4, hipMemcpyDeviceToDevice, stream);
  hipMemcpyAsync(b_cqkvg + 768, col_gate_b, 256 * 4, hipMemcpyDeviceToDevice,
                 stream);

  // ---- Phase A: MSARowAttentionWithPairBias ----
  ln256_bf_kernel<<<32768, 64, 0, stream>>>(node, ln_bf, ln_mr_g, ln_mr_b);
  pair_bias_kernel<<<65536, 64, 0, stream>>>(pair, ln_z_g, ln_z_b, b_weights,
                                             buf_bias);
  gemm_mfma_kernel<0><<<dim3(256, 8), 256, 0, stream>>>(
      ln_bf, w_rqkvg, b_rqkvg, nullptr, qkv_bf, 1024, 256);
  attn_mfma_kernel<true><<<1024, 256, 0, stream>>>(qkv_bf, buf_bias, g_bf);
  gemm_mfma_kernel<2><<<dim3(256, 2), 256, 0, stream>>>(
      g_bf, w_ro, out_bias, node, buf_node, 256, 256);

  // ---- Phase B: MSAColumnAttention ----
  ln256_bf_kernel<<<32768, 64, 0, stream>>>(buf_node, ln_bf, ln_mc_g, ln_mc_b);
  gemm_mfma_kernel<0><<<dim3(256, 8), 256, 0, stream>>>(
      ln_bf, w_cqkvg, b_cqkvg, nullptr, qkv_bf, 1024, 256);
  attn_mfma_kernel<false><<<2048, 256, 0, stream>>>(qkv_bf, nullptr, g_bf);
  gemm_mfma_kernel<2><<<dim3(256, 2), 256, 0, stream>>>(
      g_bf, w_co, col_o_b, buf_node, buf_node, 256, 256);

  // ---- Phase C: MSATransition ----
  ln256_bf_kernel<<<32768, 64, 0, stream>>>(buf_node, ln_bf, ln_t_g, ln_t_b);
  gemm_mfma_kernel<3><<<dim3(256, 8), 256, 0, stream>>>(
      ln_bf, w_t1, t_b1, nullptr, h_bf, 1024, 256);
  gemm_mfma_kernel<2><<<dim3(256, 2), 256, 0, stream>>>(
      h_bf, w_t2, t_b2, buf_node, out, 256, 1024);
}